// Round 1
// baseline (365.592 us; speedup 1.0000x reference)
//
#include <hip/hip_runtime.h>

// NormConv2d: depthwise 3x3 correlation with L2-normalized filters, divided by
// per-patch L2 norm. x: (16,3,1024,1024) fp32, w: (3,1,3,3) fp32, zero-pad 1.
// out(n,c,y,x) = sum_{r,k} x[y+r-1][x+k-1] * wn[c][r][k]  /  sqrt(sum x^2 over window)
// with wn = w / ||w||_2 per channel.

#define HH 1024
#define WW 1024
#define CC 3
#define NN 16

__global__ __launch_bounds__(256) void normconv_kernel(
    const float* __restrict__ x, const float* __restrict__ w, float* __restrict__ out)
{
    // blockIdx.x = plane*H + row ; plane = n*C + c  (row, plane block-uniform)
    const int row   = blockIdx.x & (HH - 1);
    const int plane = blockIdx.x >> 10;
    const int c     = plane % CC;

    // Normalized weights — block-uniform, compiler scalarizes (s_load + s_* ops)
    float wn[9];
    float s = 0.f;
#pragma unroll
    for (int i = 0; i < 9; ++i) { float wi = w[c * 9 + i]; wn[i] = wi; s += wi * wi; }
    const float winv = rsqrtf(s);
#pragma unroll
    for (int i = 0; i < 9; ++i) wn[i] *= winv;

    const int x0 = threadIdx.x << 2;            // 4 outputs per thread
    const float* base = x + (size_t)plane * (HH * WW);

    // v[r][0..5] = input row (row+r-1), columns x0-1 .. x0+4 (zero-padded)
    float v[3][6];
#pragma unroll
    for (int r = 0; r < 3; ++r) {
        const int y = row + r - 1;
        if (y < 0 || y >= HH) {                 // block-uniform branch (top/bottom rows)
#pragma unroll
            for (int k = 0; k < 6; ++k) v[r][k] = 0.f;
        } else {
            const float* p = base + y * WW;
            const float4 c4 = *(const float4*)(p + x0);   // 16B-aligned
            v[r][0] = (x0 > 0)        ? p[x0 - 1] : 0.f;  // left halo (predicated)
            v[r][1] = c4.x; v[r][2] = c4.y; v[r][3] = c4.z; v[r][4] = c4.w;
            v[r][5] = (x0 + 4 < WW)   ? p[x0 + 4] : 0.f;  // right halo
        }
    }

    float4 o;
    float* op = &o.x;
#pragma unroll
    for (int j = 0; j < 4; ++j) {
        float num = 0.f, sq = 0.f;
#pragma unroll
        for (int r = 0; r < 3; ++r)
#pragma unroll
            for (int k = 0; k < 3; ++k) {
                const float val = v[r][j + k];
                num += val * wn[r * 3 + k];
                sq  += val * val;
            }
        op[j] = num * rsqrtf(sq);               // num / sqrt(sq)
    }

    *(float4*)(out + (size_t)plane * (HH * WW) + (size_t)row * WW + x0) = o;
}

extern "C" void kernel_launch(void* const* d_in, const int* in_sizes, int n_in,
                              void* d_out, int out_size, void* d_ws, size_t ws_size,
                              hipStream_t stream) {
    const float* x = (const float*)d_in[0];
    const float* w = (const float*)d_in[1];
    float* out = (float*)d_out;

    const int blocks = NN * CC * HH;            // one block per output row: 49152
    normconv_kernel<<<blocks, 256, 0, stream>>>(x, w, out);
}

// Round 2
// 344.320 us; speedup vs baseline: 1.0618x; 1.0618x over previous
//
#include <hip/hip_runtime.h>

// NormConv2d: depthwise 3x3 correlation with L2-normalized filters, divided by
// per-patch L2 norm. x: (16,3,1024,1024) fp32, w: (3,1,3,3) fp32, zero-pad 1.
//
// Round 2: row-tiled sliding window. Each block computes ROWS=8 consecutive
// output rows of one plane (256 threads x 4 cols = full 1024-px width).
// 3 input rows live in registers; one new row loaded per output row ->
// logical fetch 10/8 = 1.25x (was 3x across XCDs in round 1).
// XCD swizzle: same (blockIdx & 7) == same XCD under round-robin dispatch,
// mapped to a contiguous logical tile range so tile-boundary halo rows are
// re-fetched from the same XCD's L2.

#define HH 1024
#define WW 1024
#define CC 3
#define NN 16
#define ROWS 8
#define TILES (HH / ROWS)        // 128 tiles per plane
#define NBLK (NN * CC * TILES)   // 6144 blocks

__device__ __forceinline__ void load_row(const float* __restrict__ base, int y,
                                         int x0, float* __restrict__ dst)
{
    if ((unsigned)y >= (unsigned)HH) {   // zero-pad top/bottom (block-uniform)
#pragma unroll
        for (int k = 0; k < 6; ++k) dst[k] = 0.f;
    } else {
        const float* p = base + y * WW;
        const float4 c4 = *(const float4*)(p + x0);       // 16B-aligned
        dst[0] = (x0 > 0)      ? p[x0 - 1] : 0.f;         // left halo (L1 hit)
        dst[1] = c4.x; dst[2] = c4.y; dst[3] = c4.z; dst[4] = c4.w;
        dst[5] = (x0 + 4 < WW) ? p[x0 + 4] : 0.f;         // right halo
    }
}

__global__ __launch_bounds__(256) void normconv_kernel(
    const float* __restrict__ x, const float* __restrict__ w, float* __restrict__ out)
{
    // XCD-aware swizzle: logical tile L from physical block id b such that
    // blocks with equal (b & 7) cover a contiguous range of L.
    const int b     = blockIdx.x;
    const int L     = (b & 7) * (NBLK / 8) + (b >> 3);
    const int tile  = L & (TILES - 1);
    const int plane = L >> 7;            // L / TILES
    const int c     = plane % CC;

    // Normalized weights — block-uniform, scalarized by the compiler
    float wn[9];
    float s = 0.f;
#pragma unroll
    for (int i = 0; i < 9; ++i) { float wi = w[c * 9 + i]; wn[i] = wi; s += wi * wi; }
    const float winv = rsqrtf(s);
#pragma unroll
    for (int i = 0; i < 9; ++i) wn[i] *= winv;

    const int x0 = threadIdx.x << 2;                 // 4 outputs per thread
    const int y0 = tile * ROWS;
    const float* base  = x   + (size_t)plane * (HH * WW);
    float*       obase = out + (size_t)plane * (HH * WW);

    // Rotating 3-row window: v[r][0..5] = cols x0-1 .. x0+4 of an input row
    float v[3][6];
    load_row(base, y0 - 1, x0, v[0]);
    load_row(base, y0,     x0, v[1]);

#pragma unroll
    for (int i = 0; i < ROWS; ++i) {
        const int y = y0 + i;
        load_row(base, y + 1, x0, v[(i + 2) % 3]);   // fully unrolled -> static idx
        const float* r0 = v[(i + 0) % 3];
        const float* r1 = v[(i + 1) % 3];
        const float* r2 = v[(i + 2) % 3];

        float4 o;
        float* op = &o.x;
#pragma unroll
        for (int j = 0; j < 4; ++j) {
            float num = 0.f, sq = 0.f;
#pragma unroll
            for (int k = 0; k < 3; ++k) {
                const float a0 = r0[j + k], a1 = r1[j + k], a2 = r2[j + k];
                num += a0 * wn[k] + a1 * wn[3 + k] + a2 * wn[6 + k];
                sq  += a0 * a0 + a1 * a1 + a2 * a2;
            }
            op[j] = num * rsqrtf(sq);
        }
        *(float4*)(obase + (size_t)y * WW + x0) = o;
    }
}

extern "C" void kernel_launch(void* const* d_in, const int* in_sizes, int n_in,
                              void* d_out, int out_size, void* d_ws, size_t ws_size,
                              hipStream_t stream) {
    const float* x = (const float*)d_in[0];
    const float* w = (const float*)d_in[1];
    float* out = (float*)d_out;

    normconv_kernel<<<NBLK, 256, 0, stream>>>(x, w, out);
}